// Round 1
// baseline (170.225 us; speedup 1.0000x reference)
//
#include <hip/hip_runtime.h>
#include <math.h>

// AntiAliasInterpolation2d: depthwise 13x13 gaussian blur + 4x nearest downsample,
// fused so only the 128x128 sampled output rows/cols are ever computed.
//
// x: (8, 512, 512, 32) f32 NHWC.  out: (8, 128, 128, 32) f32.
// Separable: out(r,c) = sum_i w[i] * sum_j w[j] * x(4r+i-6, 4c+j-6), zero-padded.

#define HH 512
#define WW 512
#define CC 32
#define OH 128
#define OW 128
#define KS 13
#define KA 6
#define TR 8            // output rows per block
#define TC 32           // output cols per block
#define NROWS (4*TR + 9) // 41 input rows per block (incl. halo)

struct W13 { float w[KS]; };

__global__ __launch_bounds__(256, 2)
void aa_blur_down_kernel(const float* __restrict__ x, float* __restrict__ out, W13 wk)
{
    __shared__ float ws13[KS];
    __shared__ float WV[NROWS][TR];   // vertical weight for (local input row, local output row)

    const int tid = threadIdx.x;
    if (tid == 0) {
#pragma unroll
        for (int j = 0; j < KS; ++j) ws13[j] = wk.w[j];   // static index -> SGPR -> LDS
    }
    __syncthreads();
    for (int idx = tid; idx < NROWS * TR; idx += 256) {
        int yl = idx >> 3;            // /TR
        int r  = idx & (TR - 1);      // %TR
        int i  = yl - 4 * r;          // tap index for this (row, out-row) pair
        WV[yl][r] = (i >= 0 && i < KS) ? ws13[i] : 0.0f;
    }
    __syncthreads();

    // XCD-aware bijective swizzle: 512 blocks = 8 XCDs x 64. Logical-consecutive
    // row-tiles (sharing 9-row halos) land on the same XCD's L2.
    int bid = blockIdx.x;
    int lid = (bid & 7) * 64 + (bid >> 3);
    int rt = lid & 15;          // row tile   (16)
    int ct = (lid >> 4) & 3;    // col tile   (4)
    int n  = lid >> 6;          // batch      (8)

    const int ch4 = tid & 7;    // which float4 group of the 32 channels
    const int cw  = tid >> 3;   // 0..31 output-column worker
    const int c   = ct * TC + cw;
    const int r0  = rt * TR;

    const float* xb = x + (size_t)n * HH * WW * CC + ch4 * 4;

    float4 acc[TR];
#pragma unroll
    for (int r = 0; r < TR; ++r) acc[r] = make_float4(0.f, 0.f, 0.f, 0.f);

    const int xc0 = 4 * c - KA;   // input col of tap j=0
    const int y0  = 4 * r0 - KA;  // input row of local row 0

    for (int yl = 0; yl < NROWS; ++yl) {
        int y = y0 + yl;
        if ((unsigned)y >= (unsigned)HH) continue;   // block-uniform: zero-padded row
        const float* row = xb + (size_t)y * WW * CC;

        // horizontal blur at this thread's output column (4 channels)
        float4 h = make_float4(0.f, 0.f, 0.f, 0.f);
#pragma unroll
        for (int j = 0; j < KS; ++j) {
            int xc = xc0 + j;
            if ((unsigned)xc < (unsigned)WW) {
                float4 v = *reinterpret_cast<const float4*>(row + (size_t)xc * CC);
                float wj = wk.w[j];
                h.x = fmaf(wj, v.x, h.x);
                h.y = fmaf(wj, v.y, h.y);
                h.z = fmaf(wj, v.z, h.z);
                h.w = fmaf(wj, v.w, h.w);
            }
        }

        // vertical accumulate into the 8 output rows of this tile
#pragma unroll
        for (int r = 0; r < TR; ++r) {
            float wv = WV[yl][r];    // uniform-address LDS read -> broadcast
            acc[r].x = fmaf(wv, h.x, acc[r].x);
            acc[r].y = fmaf(wv, h.y, acc[r].y);
            acc[r].z = fmaf(wv, h.z, acc[r].z);
            acc[r].w = fmaf(wv, h.w, acc[r].w);
        }
    }

#pragma unroll
    for (int r = 0; r < TR; ++r) {
        float* o = out + (((size_t)n * OH + (r0 + r)) * OW + c) * CC + ch4 * 4;
        *reinterpret_cast<float4*>(o) = acc[r];
    }
}

extern "C" void kernel_launch(void* const* d_in, const int* in_sizes, int n_in,
                              void* d_out, int out_size, void* d_ws, size_t ws_size,
                              hipStream_t stream)
{
    const float* x = (const float*)d_in[0];
    float* out = (float*)d_out;

    // Rebuild the separable gaussian weights on the host (double precision).
    // Reference: g[i]=exp(-(i-6)^2/(2*1.5^2)); k2=outer(g,g)/sum -> w[i]=g[i]/sum(g).
    W13 wk;
    double g[KS], s = 0.0;
    for (int i = 0; i < KS; ++i) {
        double d = i - (KS - 1) / 2.0;
        g[i] = exp(-(d * d) / (2.0 * 1.5 * 1.5));
        s += g[i];
    }
    for (int i = 0; i < KS; ++i) wk.w[i] = (float)(g[i] / s);

    dim3 grid(8 * 4 * 16);   // batch x col-tiles x row-tiles = 512 blocks
    aa_blur_down_kernel<<<grid, 256, 0, stream>>>(x, out, wk);
}

// Round 2
// 79.018 us; speedup vs baseline: 2.1543x; 2.1543x over previous
//
#include <hip/hip_runtime.h>
#include <math.h>

// AntiAliasInterpolation2d: depthwise 13x13 gaussian blur + 4x nearest downsample,
// fused so only the 128x128 sampled output rows/cols are ever computed.
//
// x: (8, 512, 512, 32) f32 NHWC.  out: (8, 128, 128, 32) f32.
// Separable: out(r,c) = sum_i w[i] * sum_j w[j] * x(4r+i-6, 4c+j-6), zero-padded.
//
// R2 changes vs R1 (which was latency-serialized at 237us, VGPR=32):
//  - BRANCH-FREE tap loads: clamp column address, zero the weight via cndmask.
//    All 13 float4 loads issue unconditionally -> 13-deep MLP per row instead of
//    load->waitcnt->fma serialization.
//  - Row validity folded into the WV table (weight=0), row address clamped ->
//    straight-line inner loop, no branches at all.
//  - TR 8 -> 4: grid 512 -> 1024 blocks (4 blocks/CU, ~50% occupancy).

#define HH 512
#define WW 512
#define CC 32
#define OH 128
#define OW 128
#define KS 13
#define KA 6
#define TR 4            // output rows per block
#define TC 32           // output cols per block
#define NROWS (4*TR + 9) // 25 input rows per block (incl. halo)

struct W13 { float w[KS]; };

__global__ __launch_bounds__(256, 4)
void aa_blur_down_kernel(const float* __restrict__ x, float* __restrict__ out, W13 wk)
{
    __shared__ float WV[NROWS][TR];   // vertical weight for (local input row, local output row)

    const int tid = threadIdx.x;

    // XCD-aware bijective swizzle: 1024 blocks = 8 XCDs x 128. Logical-consecutive
    // row-tiles (sharing 9-row halos) land on the same XCD's L2.
    int bid = blockIdx.x;
    int lid = (bid & 7) * 128 + (bid >> 3);
    int rt = lid & 31;          // row tile   (32)
    int ct = (lid >> 5) & 3;    // col tile   (4)
    int n  = lid >> 7;          // batch      (8)

    const int r0 = rt * TR;
    const int y0 = 4 * r0 - KA;  // input row of local row 0

    // Fill vertical-weight table; fold row-validity (zero padding) into the weight.
    for (int idx = tid; idx < NROWS * TR; idx += 256) {
        int yl = idx >> 2;            // /TR
        int r  = idx & (TR - 1);      // %TR
        int i  = yl - 4 * r;          // vertical tap index for this (row, out-row) pair
        int y  = y0 + yl;
        bool ok = (i >= 0) && (i < KS) && ((unsigned)y < (unsigned)HH);
        WV[yl][r] = ok ? wk.w[i < 0 ? 0 : (i >= KS ? KS - 1 : i)] : 0.0f;
    }
    __syncthreads();

    const int ch4 = tid & 7;    // which float4 group of the 32 channels
    const int cw  = tid >> 3;   // 0..31 output-column worker
    const int c   = ct * TC + cw;

    const float* xb = x + (size_t)n * HH * WW * CC + ch4 * 4;

    float4 acc[TR];
#pragma unroll
    for (int r = 0; r < TR; ++r) acc[r] = make_float4(0.f, 0.f, 0.f, 0.f);

    const int xc0 = 4 * c - KA;   // input col of tap j=0

    for (int yl = 0; yl < NROWS; ++yl) {
        int y  = y0 + yl;
        int yc = y < 0 ? 0 : (y >= HH ? HH - 1 : y);          // clamped address; weight 0 if invalid
        const float* row = xb + (size_t)yc * (WW * CC);

        // horizontal blur at this thread's output column (4 channels), branch-free
        float4 h = make_float4(0.f, 0.f, 0.f, 0.f);
#pragma unroll
        for (int j = 0; j < KS; ++j) {
            int xc = xc0 + j;
            bool ok = (unsigned)xc < (unsigned)WW;
            int xcc = ok ? xc : 0;                            // clamped address
            float wj = ok ? wk.w[j] : 0.0f;                   // zeroed weight (cndmask)
            float4 v = *reinterpret_cast<const float4*>(row + (size_t)xcc * CC);
            h.x = fmaf(wj, v.x, h.x);
            h.y = fmaf(wj, v.y, h.y);
            h.z = fmaf(wj, v.z, h.z);
            h.w = fmaf(wj, v.w, h.w);
        }

        // vertical accumulate into the TR output rows of this tile
#pragma unroll
        for (int r = 0; r < TR; ++r) {
            float wv = WV[yl][r];    // uniform-address LDS read -> broadcast
            acc[r].x = fmaf(wv, h.x, acc[r].x);
            acc[r].y = fmaf(wv, h.y, acc[r].y);
            acc[r].z = fmaf(wv, h.z, acc[r].z);
            acc[r].w = fmaf(wv, h.w, acc[r].w);
        }
    }

#pragma unroll
    for (int r = 0; r < TR; ++r) {
        float* o = out + (((size_t)n * OH + (r0 + r)) * OW + c) * CC + ch4 * 4;
        *reinterpret_cast<float4*>(o) = acc[r];
    }
}

extern "C" void kernel_launch(void* const* d_in, const int* in_sizes, int n_in,
                              void* d_out, int out_size, void* d_ws, size_t ws_size,
                              hipStream_t stream)
{
    const float* x = (const float*)d_in[0];
    float* out = (float*)d_out;

    // Rebuild the separable gaussian weights on the host (double precision).
    // Reference: g[i]=exp(-(i-6)^2/(2*1.5^2)); k2=outer(g,g)/sum -> w[i]=g[i]/sum(g).
    W13 wk;
    double g[KS], s = 0.0;
    for (int i = 0; i < KS; ++i) {
        double d = i - (KS - 1) / 2.0;
        g[i] = exp(-(d * d) / (2.0 * 1.5 * 1.5));
        s += g[i];
    }
    for (int i = 0; i < KS; ++i) wk.w[i] = (float)(g[i] / s);

    dim3 grid(8 * 4 * 32);   // batch x col-tiles x row-tiles = 1024 blocks
    aa_blur_down_kernel<<<grid, 256, 0, stream>>>(x, out, wk);
}

// Round 3
// 74.795 us; speedup vs baseline: 2.2759x; 1.0565x over previous
//
#include <hip/hip_runtime.h>
#include <math.h>

// AntiAliasInterpolation2d: depthwise 13x13 gaussian blur + 4x nearest downsample,
// fused so only the 128x128 sampled output rows/cols are ever computed.
//
// x: (8, 512, 512, 32) f32 NHWC.  out: (8, 128, 128, 32) f32.
// Separable: out(r,c) = sum_i w[i] * sum_j w[j] * x(4r+i-6, 4c+j-6), zero-padded.
//
// R3 changes vs R2 (79us, ~4.8x L1 traffic amplification from 13 overlapping
// global taps per row per thread):
//  - LDS row staging: each block stages its 144-pixel input row segment into
//    LDS ONCE (coalesced float4, double-buffered), taps read from LDS.
//  - XOR swizzle on the 16B chunk index kills the 8-way ds_read bank conflict:
//    worker w reads pixel p = 4*cw + j; (p>>2)&7 = (cw + j>>2)&7 is distinct
//    across the 8 workers of a wave, so chunk slot = c ^ ((p>>2)&7) puts the
//    8 workers in 8 distinct 16B slot columns -> 8 touches/bank = minimum.
//  - T14 split staging: issue next-row global loads BEFORE compute, ds_write
//    them after -> HBM latency hides under the 13 ds_read + 68 FMA.

#define HH 512
#define WW 512
#define CC 32
#define OH 128
#define OW 128
#define KS 13
#define KA 6
#define TR 4             // output rows per block
#define TC 32            // output cols per block
#define NROWS (4*TR + 9) // 25 input row-steps per block (incl. halo)
#define NPX  144         // staged pixels per row (128*4 input cols + 9 halo, rounded)
#define BUF_F4 (NPX*8)   // 1152 float4 slots per LDS row buffer (18432 B)

struct W13 { float w[KS]; };

__device__ __forceinline__ int swz(int p, int c) {
    return p * 8 + (c ^ ((p >> 2) & 7));   // float4-slot index in a row buffer
}

__global__ __launch_bounds__(256, 4)
void aa_blur_down_kernel(const float* __restrict__ x, float* __restrict__ out, W13 wk)
{
    __shared__ float4 lbuf[2][BUF_F4];
    __shared__ float WV[NROWS][TR];   // vertical weight (local input row, local output row)

    const int tid = threadIdx.x;

    // XCD-aware bijective swizzle: 1024 blocks = 8 XCDs x 128. Consecutive
    // row-tiles (sharing 9-row halos) land on the same XCD's L2.
    int bid = blockIdx.x;
    int lid = (bid & 7) * 128 + (bid >> 3);
    int rt = lid & 31;          // row tile   (32)
    int ct = (lid >> 5) & 3;    // col tile   (4)
    int n  = lid >> 7;          // batch      (8)

    const int r0 = rt * TR;
    const int y0 = 4 * r0 - KA;        // input row of local row-step 0
    const int cb = ct * (4 * TC) - KA; // input col of staged pixel 0

    // Vertical-weight table; row validity (zero padding) folded into the weight.
    for (int idx = tid; idx < NROWS * TR; idx += 256) {
        int yl = idx >> 2;            // /TR
        int r  = idx & (TR - 1);      // %TR
        int i  = yl - 4 * r;          // vertical tap index
        int y  = y0 + yl;
        bool ok = (i >= 0) && (i < KS) && ((unsigned)y < (unsigned)HH);
        WV[yl][r] = ok ? wk.w[i < 0 ? 0 : (i >= KS ? KS - 1 : i)] : 0.0f;
    }

    const int ch4 = tid & 7;    // float4 group of the 32 channels
    const int cw  = tid >> 3;   // 0..31 output-column worker
    const int c   = ct * TC + cw;

    const float* xn = x + (size_t)n * HH * WW * CC;

    float4 acc[TR];
#pragma unroll
    for (int r = 0; r < TR; ++r) acc[r] = make_float4(0.f, 0.f, 0.f, 0.f);

    // ---- staging helpers (inlined manually) ----
    // Each row-step stages BUF_F4=1152 float4: thread t handles f = t + 256k.
    // k<4 always valid; k=4 only for t<128.
#define STAGE_LOAD(SV, YL)                                                      \
    {                                                                           \
        int y  = y0 + (YL);                                                     \
        int yc = y < 0 ? 0 : (y >= HH ? HH - 1 : y);                            \
        const float* row = xn + (size_t)yc * (WW * CC);                         \
        _Pragma("unroll")                                                       \
        for (int k = 0; k < 5; ++k) {                                           \
            int f  = tid + 256 * k;                                             \
            int p  = f >> 3;                                                    \
            int cc = f & 7;                                                     \
            int gx = cb + p;                                                    \
            bool ok = (f < BUF_F4) && ((unsigned)gx < (unsigned)WW);            \
            int gxc = gx < 0 ? 0 : (gx >= WW ? WW - 1 : gx);                    \
            float4 v = *reinterpret_cast<const float4*>(row + (size_t)gxc * CC + cc * 4); \
            SV[k] = ok ? v : make_float4(0.f, 0.f, 0.f, 0.f);                   \
        }                                                                       \
    }

#define STAGE_WRITE(B, SV)                                                      \
    {                                                                           \
        _Pragma("unroll")                                                       \
        for (int k = 0; k < 5; ++k) {                                           \
            int f = tid + 256 * k;                                              \
            if (k < 4 || f < BUF_F4) {                                          \
                int p  = f >> 3;                                                \
                int cc = f & 7;                                                 \
                lbuf[B][swz(p, cc)] = SV[k];                                    \
            }                                                                   \
        }                                                                       \
    }

    // prologue: stage row-step 0 into buffer 0
    {
        float4 sv[5];
        STAGE_LOAD(sv, 0);
        STAGE_WRITE(0, sv);
    }
    __syncthreads();

    int cur = 0;
    for (int yl = 0; yl < NROWS; ++yl) {
        float4 sv[5];
        const bool more = (yl + 1 < NROWS);
        if (more) STAGE_LOAD(sv, yl + 1);   // issue loads early (T14)

        // horizontal blur from LDS (swizzled, conflict-free)
        float4 h = make_float4(0.f, 0.f, 0.f, 0.f);
#pragma unroll
        for (int j = 0; j < KS; ++j) {
            int p = 4 * cw + j;
            float4 v = lbuf[cur][swz(p, ch4)];
            float wj = wk.w[j];
            h.x = fmaf(wj, v.x, h.x);
            h.y = fmaf(wj, v.y, h.y);
            h.z = fmaf(wj, v.z, h.z);
            h.w = fmaf(wj, v.w, h.w);
        }

        // vertical accumulate into the TR output rows
#pragma unroll
        for (int r = 0; r < TR; ++r) {
            float wv = WV[yl][r];    // uniform-address LDS read -> broadcast
            acc[r].x = fmaf(wv, h.x, acc[r].x);
            acc[r].y = fmaf(wv, h.y, acc[r].y);
            acc[r].z = fmaf(wv, h.z, acc[r].z);
            acc[r].w = fmaf(wv, h.w, acc[r].w);
        }

        if (more) STAGE_WRITE(cur ^ 1, sv); // write-late into the other buffer
        __syncthreads();
        cur ^= 1;
    }

#pragma unroll
    for (int r = 0; r < TR; ++r) {
        float* o = out + (((size_t)n * OH + (r0 + r)) * OW + c) * CC + ch4 * 4;
        *reinterpret_cast<float4*>(o) = acc[r];
    }
}

extern "C" void kernel_launch(void* const* d_in, const int* in_sizes, int n_in,
                              void* d_out, int out_size, void* d_ws, size_t ws_size,
                              hipStream_t stream)
{
    const float* x = (const float*)d_in[0];
    float* out = (float*)d_out;

    // Rebuild the separable gaussian weights on the host (double precision).
    // Reference: g[i]=exp(-(i-6)^2/(2*1.5^2)); w[i]=g[i]/sum(g); k2=outer(w,w).
    W13 wk;
    double g[KS], s = 0.0;
    for (int i = 0; i < KS; ++i) {
        double d = i - (KS - 1) / 2.0;
        g[i] = exp(-(d * d) / (2.0 * 1.5 * 1.5));
        s += g[i];
    }
    for (int i = 0; i < KS; ++i) wk.w[i] = (float)(g[i] / s);

    dim3 grid(8 * 4 * 32);   // batch x col-tiles x row-tiles = 1024 blocks
    aa_blur_down_kernel<<<grid, 256, 0, stream>>>(x, out, wk);
}

// Round 4
// 53.611 us; speedup vs baseline: 3.1752x; 1.3951x over previous
//
#include <hip/hip_runtime.h>
#include <math.h>

// AntiAliasInterpolation2d: depthwise 13x13 gaussian blur + 4x nearest downsample,
// fused so only the 128x128 sampled output rows/cols are ever computed.
//
// x: (8, 512, 512, 32) f32 NHWC.  out: (8, 128, 128, 32) f32.
// Separable: out(r,c) = sum_i w[i] * sum_j w[j] * x(4r+i-6, 4c+j-6), zero-padded.
//
// R4 changes vs R3 (74.8us == staging-traffic roofline: 1.76x halo amplification):
//  - TR 4 -> 8: row-halo amplification 25/16 -> 41/32.
//  - SERPENTINE sweep: odd row-tiles iterate rows bottom-to-top, so vertically
//    adjacent tiles touch their 9 shared halo rows at the SAME phase of the
//    sweep -> the re-read hits the same-XCD L2 (aligned by the XCD swizzle)
//    instead of HBM. Col-halo is phase-aligned by construction.

#define HH 512
#define WW 512
#define CC 32
#define OH 128
#define OW 128
#define KS 13
#define KA 6
#define TR 8             // output rows per block
#define TC 32            // output cols per block
#define NROWS (4*TR + 9) // 41 input row-steps per block (incl. halo)
#define NPX  144         // staged pixels per row (4*TC + 9 halo, padded to 144)
#define BUF_F4 (NPX*8)   // 1152 float4 slots per LDS row buffer (18432 B)

struct W13 { float w[KS]; };

__device__ __forceinline__ int swz(int p, int c) {
    return p * 8 + (c ^ ((p >> 2) & 7));   // float4-slot index in a row buffer
}

__global__ __launch_bounds__(256, 2)
void aa_blur_down_kernel(const float* __restrict__ x, float* __restrict__ out, W13 wk)
{
    __shared__ float4 lbuf[2][BUF_F4];
    __shared__ float WV[NROWS][TR];   // vertical weight (local input row, local output row)

    const int tid = threadIdx.x;

    // XCD-aware bijective swizzle: 512 blocks = 8 XCDs x 64. Consecutive lids
    // (rt-neighbors, then ct-neighbors) land on the same XCD's L2.
    int bid = blockIdx.x;
    int lid = (bid & 7) * 64 + (bid >> 3);
    int rt = lid & 15;          // row tile   (16)
    int ct = (lid >> 4) & 3;    // col tile   (4)
    int n  = lid >> 6;          // batch      (8)

    const int r0 = rt * TR;
    const int y0 = 4 * r0 - KA;        // input row of local row-step 0
    const int cb = ct * (4 * TC) - KA; // input col of staged pixel 0

    // Vertical-weight table; row validity (zero padding) folded into the weight.
    for (int idx = tid; idx < NROWS * TR; idx += 256) {
        int yl = idx >> 3;            // /TR
        int r  = idx & (TR - 1);      // %TR
        int i  = yl - 4 * r;          // vertical tap index
        int y  = y0 + yl;
        bool ok = (i >= 0) && (i < KS) && ((unsigned)y < (unsigned)HH);
        WV[yl][r] = ok ? wk.w[i < 0 ? 0 : (i >= KS ? KS - 1 : i)] : 0.0f;
    }

    const int ch4 = tid & 7;    // float4 group of the 32 channels
    const int cw  = tid >> 3;   // 0..31 output-column worker
    const int c   = ct * TC + cw;

    const float* xn = x + (size_t)n * HH * WW * CC;

    float4 acc[TR];
#pragma unroll
    for (int r = 0; r < TR; ++r) acc[r] = make_float4(0.f, 0.f, 0.f, 0.f);

    const int xc0 = 4 * c - KA;   // unused; kept for clarity of mapping
    (void)xc0;

    // Serpentine: even rt sweeps top->bottom, odd rt bottom->top, so halo rows
    // shared with the vertical neighbor are touched at the same sweep phase.
    const bool up  = (rt & 1);
    const int  ylS = up ? (NROWS - 1) : 0;
    const int  dir = up ? -1 : 1;

    // ---- staging helpers ----
    // Each row-step stages BUF_F4=1152 float4: thread t handles f = t + 256k.
#define STAGE_LOAD(SV, YL)                                                      \
    {                                                                           \
        int y  = y0 + (YL);                                                     \
        int yc = y < 0 ? 0 : (y >= HH ? HH - 1 : y);                            \
        const float* row = xn + (size_t)yc * (WW * CC);                         \
        _Pragma("unroll")                                                       \
        for (int k = 0; k < 5; ++k) {                                           \
            int f  = tid + 256 * k;                                             \
            int p  = f >> 3;                                                    \
            int cc = f & 7;                                                     \
            int gx = cb + p;                                                    \
            bool ok = (f < BUF_F4) && ((unsigned)gx < (unsigned)WW);            \
            int gxc = gx < 0 ? 0 : (gx >= WW ? WW - 1 : gx);                    \
            float4 v = *reinterpret_cast<const float4*>(row + (size_t)gxc * CC + cc * 4); \
            SV[k] = ok ? v : make_float4(0.f, 0.f, 0.f, 0.f);                   \
        }                                                                       \
    }

#define STAGE_WRITE(B, SV)                                                      \
    {                                                                           \
        _Pragma("unroll")                                                       \
        for (int k = 0; k < 5; ++k) {                                           \
            int f = tid + 256 * k;                                              \
            if (k < 4 || f < BUF_F4) {                                          \
                int p  = f >> 3;                                                \
                int cc = f & 7;                                                 \
                lbuf[B][swz(p, cc)] = SV[k];                                    \
            }                                                                   \
        }                                                                       \
    }

    // prologue: stage first row-step into buffer 0
    {
        float4 sv[5];
        STAGE_LOAD(sv, ylS);
        STAGE_WRITE(0, sv);
    }
    __syncthreads();

    int cur = 0;
    for (int s = 0; s < NROWS; ++s) {
        const int yl = ylS + dir * s;
        float4 sv[5];
        const bool more = (s + 1 < NROWS);
        if (more) STAGE_LOAD(sv, yl + dir);   // issue next-row loads early (T14)

        // horizontal blur from LDS (swizzled, conflict-free)
        float4 h = make_float4(0.f, 0.f, 0.f, 0.f);
#pragma unroll
        for (int j = 0; j < KS; ++j) {
            int p = 4 * cw + j;
            float4 v = lbuf[cur][swz(p, ch4)];
            float wj = wk.w[j];
            h.x = fmaf(wj, v.x, h.x);
            h.y = fmaf(wj, v.y, h.y);
            h.z = fmaf(wj, v.z, h.z);
            h.w = fmaf(wj, v.w, h.w);
        }

        // vertical accumulate into the TR output rows
#pragma unroll
        for (int r = 0; r < TR; ++r) {
            float wv = WV[yl][r];    // uniform-address LDS read -> broadcast
            acc[r].x = fmaf(wv, h.x, acc[r].x);
            acc[r].y = fmaf(wv, h.y, acc[r].y);
            acc[r].z = fmaf(wv, h.z, acc[r].z);
            acc[r].w = fmaf(wv, h.w, acc[r].w);
        }

        if (more) STAGE_WRITE(cur ^ 1, sv); // write-late into the other buffer
        __syncthreads();
        cur ^= 1;
    }

#pragma unroll
    for (int r = 0; r < TR; ++r) {
        float* o = out + (((size_t)n * OH + (r0 + r)) * OW + c) * CC + ch4 * 4;
        *reinterpret_cast<float4*>(o) = acc[r];
    }
}

extern "C" void kernel_launch(void* const* d_in, const int* in_sizes, int n_in,
                              void* d_out, int out_size, void* d_ws, size_t ws_size,
                              hipStream_t stream)
{
    const float* x = (const float*)d_in[0];
    float* out = (float*)d_out;

    // Rebuild the separable gaussian weights on the host (double precision).
    // Reference: g[i]=exp(-(i-6)^2/(2*1.5^2)); w[i]=g[i]/sum(g); k2=outer(w,w).
    W13 wk;
    double g[KS], s = 0.0;
    for (int i = 0; i < KS; ++i) {
        double d = i - (KS - 1) / 2.0;
        g[i] = exp(-(d * d) / (2.0 * 1.5 * 1.5));
        s += g[i];
    }
    for (int i = 0; i < KS; ++i) wk.w[i] = (float)(g[i] / s);

    dim3 grid(8 * 4 * 16);   // batch x col-tiles x row-tiles = 512 blocks
    aa_blur_down_kernel<<<grid, 256, 0, stream>>>(x, out, wk);
}